// Round 5
// baseline (4269.391 us; speedup 1.0000x reference)
//
#include <hip/hip_runtime.h>
#include <hip/hip_bf16.h>

typedef __hip_bfloat16 bf16;
typedef __attribute__((ext_vector_type(8))) short s16x8;
typedef __attribute__((ext_vector_type(4))) float f32x4;
typedef __attribute__((ext_vector_type(2))) float f32x2;

#define B_TOT 1024
#define T_LEN 256
#define H_DIM 256
#define PRED_LEN 16

__device__ __forceinline__ float b2f(short u) {
  union { unsigned int i; float f; } c;
  c.i = ((unsigned int)(unsigned short)u) << 16;
  return c.f;
}
__device__ __forceinline__ float fsig(float x) {
  return __builtin_amdgcn_rcpf(1.f + __expf(-x));
}
__device__ __forceinline__ float ftanh(float x) {
  return 1.f - 2.f * __builtin_amdgcn_rcpf(1.f + __expf(2.f * x));
}
__device__ __forceinline__ f32x4 mfma16(s16x8 a, s16x8 b, f32x4 c) {
  return __builtin_amdgcn_mfma_f32_16x16x32_bf16(a, b, c, 0, 0, 0);
}
template <int HI>
__device__ __forceinline__ f32x2 fp8pk2f(unsigned int pk) {
  return __builtin_amdgcn_cvt_pk_f32_fp8(pk, HI);   // HI immediate
}
__device__ __forceinline__ unsigned char f2fp8(float v) {
  return (unsigned char)(__builtin_amdgcn_cvt_pk_fp8_f32(v, v, 0, 0) & 0xff);
}

// ---------- Kernel 0: pack fp32 weights -> bf16 ws layouts ------------------
// encW  (768x288): rows 0..511 (r,z): [Whh | Wih(3) | 0]; rows 512..767 (n): [Whh | 0]
// wtEncP(256x288): [Wt[:,256:512] | 0]   wtDec(256x256): Wt[:,0:256]
// whhD  (768x256): dec_Whh               wihPD(768x288): [dec_Wih(265) | 0]
__global__ __launch_bounds__(256) void convert_kernel(
    const float* __restrict__ eWhh, const float* __restrict__ eWih,
    const float* __restrict__ Wt,   const float* __restrict__ dWhh,
    const float* __restrict__ dWih,
    bf16* __restrict__ encW, bf16* __restrict__ wtEncP, bf16* __restrict__ wtDec,
    bf16* __restrict__ whhD, bf16* __restrict__ wihPD)
{
  int i = blockIdx.x*256 + threadIdx.x;
  if (i < 768*288) {
    int g = i / 288, k = i - g*288;
    float v = (k < 256) ? eWhh[g*256+k]
            : (k < 259 && g < 512) ? eWih[g*3 + (k-256)] : 0.f;
    encW[i] = __float2bfloat16(v);
    wihPD[i] = __float2bfloat16((k < 265) ? dWih[g*265 + k] : 0.f);
  }
  if (i < 256*288) {
    int g = i / 288, k = i - g*288;
    wtEncP[i] = __float2bfloat16((k < 256) ? Wt[g*512 + 256 + k] : 0.f);
  }
  if (i < 256*256) {
    int g = i >> 8, k = i & 255;
    wtDec[i] = __float2bfloat16(Wt[g*512 + k]);
  }
  if (i < 768*256) whhD[i] = __float2bfloat16(dWhh[i]);
}

// ---------- Kernel 1: per-(b,t) agent attention -> timestep_reprs (f32) ----
__global__ __launch_bounds__(256) void agent_attn_kernel(
    const float* __restrict__ x, const float* __restrict__ Wa,
    const float* __restrict__ ba, const float* __restrict__ va,
    float* __restrict__ treprs)
{
  __shared__ float w0[256], w1[256], w2[256], baL[256], vaL[256];
  int tid = threadIdx.x;
  w0[tid] = Wa[tid*3+0];
  w1[tid] = Wa[tid*3+1];
  w2[tid] = Wa[tid*3+2];
  baL[tid] = ba[tid];
  vaL[tid] = va[tid];
  __syncthreads();
  long idx = (long)blockIdx.x * 256 + tid;   // b*T + t
  float xa[9];
  #pragma unroll
  for (int i = 0; i < 9; ++i) xa[i] = x[idx*9 + i];
  float s0 = 0.f, s1 = 0.f, s2 = 0.f;
  for (int h = 0; h < 256; ++h) {
    float a0 = w0[h], a1 = w1[h], a2 = w2[h], bb = baL[h], vv = vaL[h];
    s0 += ftanh(a0*xa[0] + a1*xa[1] + a2*xa[2] + bb) * vv;
    s1 += ftanh(a0*xa[3] + a1*xa[4] + a2*xa[5] + bb) * vv;
    s2 += ftanh(a0*xa[6] + a1*xa[7] + a2*xa[8] + bb) * vv;
  }
  float mx = fmaxf(s0, fmaxf(s1, s2));
  float e0 = __expf(s0-mx), e1 = __expf(s1-mx), e2 = __expf(s2-mx);
  float inv = __builtin_amdgcn_rcpf(e0+e1+e2);
  e0 *= inv; e1 *= inv; e2 *= inv;
  treprs[idx*3+0] = e0*xa[0] + e1*xa[3] + e2*xa[6];
  treprs[idx*3+1] = e0*xa[1] + e1*xa[4] + e2*xa[7];
  treprs[idx*3+2] = e0*xa[2] + e1*xa[5] + e2*xa[8];
}

// ---------- Kernel 2: persistent encoder GRU scan + fused enc_proj ---------
// 64 wgs x 512 thr; wg owns 16 batch rows for all 256 steps (batch-local).
// Gates r,z fully from MFMA over A=[h|x] (K=288); n-gate x-part = 3 VALU FMAs.
// enc_out and enc_proj emitted as fp8 e4m3.
__global__ __launch_bounds__(512) void encoder_kernel(
    const bf16* __restrict__ encW, const bf16* __restrict__ wtEncP,
    const float* __restrict__ eWih, const float* __restrict__ ebih,
    const float* __restrict__ ebhh, const float* __restrict__ treprs,
    unsigned char* __restrict__ eo8, unsigned char* __restrict__ ep8,
    float* __restrict__ h_enc)
{
  __shared__ __align__(16) float hf[16*260];          // fp32 recurrent state
  __shared__ __align__(16) bf16  hb[16*296];          // [h(256) | x(3) | 0-pad]
  __shared__ __align__(16) unsigned char projb8[2][16*264];  // fp8 proj stage
  __shared__ __align__(16) f32x4 wihnL[256];          // (w0,w1,w2,bih_n)
  __shared__ float bsumL[512];                        // bih+bhh for r,z
  __shared__ float bhhnL[256];
  __shared__ float xtL[2][64];

  const int tid = threadIdx.x;
  const int b0 = blockIdx.x * 16;

  for (int i = tid; i < 512; i += 512) bsumL[i] = ebih[i] + ebhh[i];
  for (int i = tid; i < 256; i += 512) {
    f32x4 w;
    w.x = eWih[(512+i)*3+0];
    w.y = eWih[(512+i)*3+1];
    w.z = eWih[(512+i)*3+2];
    w.w = ebih[512+i];
    wihnL[i] = w;
    bhhnL[i] = ebhh[512+i];
  }
  for (int i = tid; i < 16*260; i += 512) hf[i] = 0.f;
  for (int i = tid; i < 16*296; i += 512) hb[i] = __float2bfloat16(0.f);
  if (tid < 64) {
    int m = tid >> 2, f = tid & 3;
    float v = (f < 3) ? treprs[((long)(b0+m)*T_LEN + 0)*3 + f] : 0.f;
    xtL[0][tid] = v;
    if (f < 3) hb[m*296 + 256 + f] = __float2bfloat16(v);
  }
  __syncthreads();

  const int lane = tid & 63;
  const int wv   = tid >> 6;      // 0..7
  const int nrow = lane & 15;
  const int quad = lane >> 4;

  // wave tile set: r:{2w,2w+1} z:{16+..} n:{32+..} proj:{48+..}
  const bf16* bptr[8];
  #pragma unroll
  for (int u = 0; u < 8; ++u) {
    int tile = (u < 2) ? (2*wv + u)
             : (u < 4) ? (16 + 2*wv + (u-2))
             : (u < 6) ? (32 + 2*wv + (u-4))
                       : (48 + 2*wv + (u-6));
    int g = tile*16 + nrow;
    bptr[u] = (g < 768) ? (encW + (long)g*288 + quad*8)
                        : (wtEncP + (long)(g-768)*288 + quad*8);
  }

  s16x8 afr[9];
  for (int t = 0; t <= 257; ++t) {
    if (t <= 256) {
      #pragma unroll
      for (int kc = 0; kc < 9; ++kc)
        afr[kc] = *(const s16x8*)&hb[nrow*296 + kc*32 + quad*8];
      if (t >= 1) {   // coalesced fp8 enc_out[t-1] from hb
        int row = tid >> 5;
        int c8 = (tid & 31) * 8;
        s16x8 hv = *(const s16x8*)&hb[row*296 + c8];
        unsigned int lo = 0, hi = 0;
        lo = __builtin_amdgcn_cvt_pk_fp8_f32(b2f(hv[0]), b2f(hv[1]), lo, 0);
        lo = __builtin_amdgcn_cvt_pk_fp8_f32(b2f(hv[2]), b2f(hv[3]), lo, 1);
        hi = __builtin_amdgcn_cvt_pk_fp8_f32(b2f(hv[4]), b2f(hv[5]), hi, 0);
        hi = __builtin_amdgcn_cvt_pk_fp8_f32(b2f(hv[6]), b2f(hv[7]), hi, 1);
        uint2 w; w.x = lo; w.y = hi;
        *(uint2*)(eo8 + ((long)(b0+row)*T_LEN + (t-1))*H_DIM + c8) = w;
      }
    }
    __syncthreads();   // afr reads + writeout done before hb rewrite

    if (t < 256) {
      f32x4 acc[8] = {};
      #pragma unroll
      for (int kc = 0; kc < 9; ++kc) {
        #pragma unroll
        for (int u = 0; u < 8; ++u) {
          s16x8 bw = *(const s16x8*)(bptr[u] + kc*32);
          acc[u] = mfma16(afr[kc], bw, acc[u]);
        }
      }
      // stage proj tiles (proj of h entering this step = enc_proj[t-1]) as fp8
      #pragma unroll
      for (int u = 6; u < 8; ++u) {
        int p = (2*wv + (u-6))*16 + nrow;
        #pragma unroll
        for (int r = 0; r < 4; ++r)
          projb8[t & 1][(quad*4+r)*264 + p] = f2fp8(acc[u][r]);
      }
      // in-register GRU combine -> h_t
      #pragma unroll
      for (int r = 0; r < 4; ++r) {
        int m = quad*4 + r;
        float x0 = xtL[t & 1][m*4+0];
        float x1 = xtL[t & 1][m*4+1];
        float x2 = xtL[t & 1][m*4+2];
        #pragma unroll
        for (int c = 0; c < 2; ++c) {
          int j = wv*32 + c*16 + nrow;
          float rg = fsig(acc[c][r]   + bsumL[j]);
          float zg = fsig(acc[2+c][r] + bsumL[256+j]);
          f32x4 wn = wihnL[j];
          float gin = wn.x*x0 + wn.y*x1 + wn.z*x2 + wn.w;
          float ng = ftanh(gin + rg*(acc[4+c][r] + bhhnL[j]));
          float hold = hf[m*260 + j];
          float hnew = ng + zg*(hold - ng);
          hf[m*260 + j] = hnew;
          hb[m*296 + j] = __float2bfloat16(hnew);
        }
      }
      // prefetch next xt
      if (t < 255 && tid < 64) {
        int m = tid >> 2, f = tid & 3;
        float v = (f < 3) ? treprs[((long)(b0+m)*T_LEN + (t+1))*3 + f] : 0.f;
        xtL[(t+1)&1][tid] = v;
        if (f < 3) hb[m*296 + 256 + f] = __float2bfloat16(v);
      }
    } else if (t == 256) {  // tail: proj of h_256 (= enc_out[255]) only
      f32x4 pacc[2] = {};
      #pragma unroll
      for (int kc = 0; kc < 9; ++kc) {
        #pragma unroll
        for (int u = 0; u < 2; ++u) {
          s16x8 bw = *(const s16x8*)(bptr[6+u] + kc*32);
          pacc[u] = mfma16(afr[kc], bw, pacc[u]);
        }
      }
      #pragma unroll
      for (int u = 0; u < 2; ++u) {
        int p = (2*wv + u)*16 + nrow;
        #pragma unroll
        for (int r = 0; r < 4; ++r)
          projb8[0][(quad*4+r)*264 + p] = f2fp8(pacc[u][r]);
      }
    }

    // coalesced fp8 write of enc_proj[t-2] from the other buffer
    if (t >= 2) {
      int row = tid >> 5;
      int c8 = (tid & 31) * 8;
      uint2 w = *(const uint2*)&projb8[(t-1)&1][row*264 + c8];
      *(uint2*)(ep8 + ((long)(b0+row)*T_LEN + (t-2))*H_DIM + c8) = w;
    }
    __syncthreads();
  }

  for (int i = tid; i < 16*256; i += 512) {
    int m = i >> 8, j = i & 255;
    h_enc[(long)(b0+m)*H_DIM + j] = hf[m*260 + j];
  }
}

// ---------- Kernel 3: persistent decoder (attention + GRU), 16 steps -------
// 256 wgs x 512 thr; wg owns 4 batch rows (batch-local, no grid sync).
__global__ __launch_bounds__(512) void decoder_kernel(
    const float* __restrict__ x, const bf16* __restrict__ wtDec,
    const float* __restrict__ bt, const float* __restrict__ vt,
    const bf16* __restrict__ wihPD, const bf16* __restrict__ whhD,
    const float* __restrict__ dbih, const float* __restrict__ dbhh,
    const float* __restrict__ Wfc, const float* __restrict__ bfc,
    const unsigned char* __restrict__ eo8, const unsigned char* __restrict__ ep8,
    const float* __restrict__ h_enc, float* __restrict__ out)
{
  __shared__ __align__(16) float hfL[4*260];
  __shared__ __align__(16) bf16  hbL[16*264];   // rows 4..15 stay zero
  __shared__ __align__(16) float qL[4*260];
  __shared__ float twL[4*260];
  __shared__ __align__(16) bf16  inpb[16*296];  // [dec_in(9) | ctx(256) | 0-pad]
  __shared__ __align__(16) float vtL[256];
  __shared__ float btL[256];
  __shared__ float bihL[768];
  __shared__ float bhhL[768];
  __shared__ __align__(16) float WfcL[9*260];
  __shared__ float bfcL[9];
  __shared__ float decin[48];
  __shared__ __align__(16) float scratch[4096]; // scores / ctx partials / pp

  const int tid = threadIdx.x;
  const int b0 = blockIdx.x * 4;

  for (int i = tid; i < 256; i += 512) { vtL[i] = vt[i]; btL[i] = bt[i]; }
  for (int i = tid; i < 768; i += 512) { bihL[i] = dbih[i]; bhhL[i] = dbhh[i]; }
  for (int i = tid; i < 9*256; i += 512) { int o = i >> 8, k = i & 255; WfcL[o*260+k] = Wfc[i]; }
  if (tid < 9) bfcL[tid] = bfc[tid];
  for (int i = tid; i < 4*260; i += 512) { int m = i/260, j = i - m*260; hfL[i] = (j < 256) ? h_enc[(long)(b0+m)*H_DIM + j] : 0.f; }
  for (int i = tid; i < 16*264; i += 512) hbL[i] = __float2bfloat16(0.f);
  for (int i = tid; i < 16*296; i += 512) inpb[i] = __float2bfloat16(0.f);
  if (tid < 36) { int b = tid/9, o = tid - b*9; decin[b*12+o] = x[((long)(b0+b)*T_LEN + (T_LEN-1))*9 + o]; }
  __syncthreads();

  const int lane = tid & 63;
  const int wv   = tid >> 6;
  const int nrow = lane & 15;
  const int quad = lane >> 4;

  const bf16* qptr[2];
  #pragma unroll
  for (int u = 0; u < 2; ++u) {
    int g = wv*32 + u*16 + nrow;
    qptr[u] = wtDec + (long)g*H_DIM + quad*8;
  }
  const bf16* giptr[6];
  const bf16* ghptr[6];
  #pragma unroll
  for (int u = 0; u < 6; ++u) {
    int tile = (u < 2) ? (2*wv + u) : (u < 4) ? (16 + 2*wv + (u-2)) : (32 + 2*wv + (u-4));
    int g = tile*16 + nrow;
    giptr[u] = wihPD + (long)g*288 + quad*8;
    ghptr[u] = whhD + (long)g*H_DIM + quad*8;
  }

  for (int s = 0; s < PRED_LEN; ++s) {
    // 1. stage h (bf16) for MFMA A-operand
    for (int i = tid; i < 4*256; i += 512) {
      int m = i >> 8, j = i & 255;
      hbL[m*264 + j] = __float2bfloat16(hfL[m*260 + j]);
    }
    __syncthreads();

    // 2. q = h @ Wt_dec^T + bt
    {
      f32x4 qacc[2] = {};
      #pragma unroll
      for (int kc = 0; kc < 8; ++kc) {
        s16x8 a = *(const s16x8*)&hbL[nrow*264 + kc*32 + quad*8];
        #pragma unroll
        for (int u = 0; u < 2; ++u) {
          s16x8 bw = *(const s16x8*)(qptr[u] + kc*32);
          qacc[u] = mfma16(a, bw, qacc[u]);
        }
      }
      if (quad == 0) {
        #pragma unroll
        for (int u = 0; u < 2; ++u) {
          int g = wv*32 + u*16 + nrow;
          #pragma unroll
          for (int r = 0; r < 4; ++r)
            qL[r*260 + g] = qacc[u][r] + btL[g];
        }
      }
    }
    __syncthreads();

    // 3. scores[b][t] = sum_g tanh(ep8 + q) * vt   (fp8 decode)
    {
      int bb = tid >> 7, tt = tid & 127;
      #pragma unroll
      for (int p = 0; p < 2; ++p) {
        int t = tt + p*128;
        const uint4* ep4 = (const uint4*)(ep8 + ((long)(b0+bb)*T_LEN + t)*H_DIM);
        const float* qrow = &qL[bb*260];
        float ssum = 0.f;
        for (int kc = 0; kc < 16; ++kc) {
          uint4 pv = ep4[kc];
          float vals[16];
          f32x2 d;
          d = fp8pk2f<0>(pv.x); vals[0]=d.x;  vals[1]=d.y;
          d = fp8pk2f<1>(pv.x); vals[2]=d.x;  vals[3]=d.y;
          d = fp8pk2f<0>(pv.y); vals[4]=d.x;  vals[5]=d.y;
          d = fp8pk2f<1>(pv.y); vals[6]=d.x;  vals[7]=d.y;
          d = fp8pk2f<0>(pv.z); vals[8]=d.x;  vals[9]=d.y;
          d = fp8pk2f<1>(pv.z); vals[10]=d.x; vals[11]=d.y;
          d = fp8pk2f<0>(pv.w); vals[12]=d.x; vals[13]=d.y;
          d = fp8pk2f<1>(pv.w); vals[14]=d.x; vals[15]=d.y;
          #pragma unroll
          for (int j = 0; j < 16; ++j)
            ssum += ftanh(vals[j] + qrow[kc*16+j]) * vtL[kc*16+j];
        }
        scratch[bb*256 + t] = ssum;
      }
    }
    __syncthreads();

    // 4. softmax over t (wave b handles batch row b)
    if (wv < 4) {
      float v4[4];
      float mx = -1e30f;
      #pragma unroll
      for (int i = 0; i < 4; ++i) { v4[i] = scratch[wv*256 + lane + 64*i]; mx = fmaxf(mx, v4[i]); }
      #pragma unroll
      for (int off = 1; off < 64; off <<= 1) mx = fmaxf(mx, __shfl_xor(mx, off));
      float sum = 0.f;
      #pragma unroll
      for (int i = 0; i < 4; ++i) { v4[i] = __expf(v4[i] - mx); sum += v4[i]; }
      #pragma unroll
      for (int off = 1; off < 64; off <<= 1) sum += __shfl_xor(sum, off);
      float inv = __builtin_amdgcn_rcpf(sum);
      #pragma unroll
      for (int i = 0; i < 4; ++i) twL[wv*260 + lane + 64*i] = v4[i] * inv;
    }
    __syncthreads();

    // 5. context: thread (tq,b,h8) accumulates 8 h-cols over 64 t's (fp8 eo)
    {
      int tq = tid >> 7, b = (tid >> 5) & 3, h8 = (tid & 31) * 8;
      const unsigned char* eob = eo8 + ((long)(b0+b)*T_LEN + tq*64)*H_DIM + h8;
      const float* tw = &twL[b*260 + tq*64];
      float c[8] = {0.f,0.f,0.f,0.f,0.f,0.f,0.f,0.f};
      for (int t = 0; t < 64; ++t) {
        uint2 ev = *(const uint2*)(eob + (long)t*H_DIM);
        float w = tw[t];
        f32x2 d;
        d = fp8pk2f<0>(ev.x); c[0] += w*d.x; c[1] += w*d.y;
        d = fp8pk2f<1>(ev.x); c[2] += w*d.x; c[3] += w*d.y;
        d = fp8pk2f<0>(ev.y); c[4] += w*d.x; c[5] += w*d.y;
        d = fp8pk2f<1>(ev.y); c[6] += w*d.x; c[7] += w*d.y;
      }
      #pragma unroll
      for (int j = 0; j < 8; ++j) scratch[tq*1024 + b*256 + h8 + j] = c[j];
    }
    __syncthreads();
    // reduce 4 t-quarters -> inpb ctx
    {
      #pragma unroll
      for (int p = 0; p < 2; ++p) {
        int idx = tid + p*512;
        int b = idx >> 8, h = idx & 255;
        float sum = scratch[b*256 + h] + scratch[1024 + b*256 + h]
                  + scratch[2048 + b*256 + h] + scratch[3072 + b*256 + h];
        inpb[b*296 + 9 + h] = __float2bfloat16(sum);
      }
      if (tid < 36) { int b = tid/9, o = tid - b*9; inpb[b*296 + o] = __float2bfloat16(decin[b*12 + o]); }
    }
    __syncthreads();

    // 6. GRU gates (gi: K=288 padded, gh: K=256) + in-register combine
    {
      f32x4 gia[6] = {};
      #pragma unroll
      for (int kc = 0; kc < 9; ++kc) {
        s16x8 a = *(const s16x8*)&inpb[nrow*296 + kc*32 + quad*8];
        #pragma unroll
        for (int u = 0; u < 6; ++u) {
          s16x8 bw = *(const s16x8*)(giptr[u] + kc*32);
          gia[u] = mfma16(a, bw, gia[u]);
        }
      }
      f32x4 gha[6] = {};
      #pragma unroll
      for (int kc = 0; kc < 8; ++kc) {
        s16x8 a = *(const s16x8*)&hbL[nrow*264 + kc*32 + quad*8];
        #pragma unroll
        for (int u = 0; u < 6; ++u) {
          s16x8 bw = *(const s16x8*)(ghptr[u] + kc*32);
          gha[u] = mfma16(a, bw, gha[u]);
        }
      }
      if (quad == 0) {  // C rows 0..3 (= batch rows) live in quad 0
        #pragma unroll
        for (int c = 0; c < 2; ++c) {
          int j = wv*32 + c*16 + nrow;
          #pragma unroll
          for (int r = 0; r < 4; ++r) {
            float rg = fsig(gia[c][r]   + bihL[j]     + gha[c][r]   + bhhL[j]);
            float zg = fsig(gia[2+c][r] + bihL[256+j] + gha[2+c][r] + bhhL[256+j]);
            float ng = ftanh(gia[4+c][r] + bihL[512+j] + rg*(gha[4+c][r] + bhhL[512+j]));
            float hold = hfL[r*260 + j];
            hfL[r*260 + j] = ng + zg*(hold - ng);
          }
        }
      }
    }
    __syncthreads();

    // 7. pred = h_new @ Wfc^T + bfc ; feed back and emit
    if (tid < 288) {
      int b = tid / 72, rem = tid - b*72;
      int o = rem >> 3, ch = rem & 7;
      float ps = 0.f;
      #pragma unroll
      for (int k = ch*32; k < ch*32 + 32; ++k)
        ps += hfL[b*260 + k] * WfcL[o*260 + k];
      scratch[tid] = ps;
    }
    __syncthreads();
    if (tid < 36) {
      int b = tid / 9, o = tid - b*9;
      float sum = bfcL[o];
      #pragma unroll
      for (int ch = 0; ch < 8; ++ch) sum += scratch[b*72 + o*8 + ch];
      out[((long)(b0+b)*PRED_LEN + s)*9 + o] = sum;
      decin[b*12 + o] = sum;
    }
    __syncthreads();
  }
}

extern "C" void kernel_launch(void* const* d_in, const int* in_sizes, int n_in,
                              void* d_out, int out_size, void* d_ws, size_t ws_size,
                              hipStream_t stream)
{
  const float* x    = (const float*)d_in[0];
  const float* Wa   = (const float*)d_in[1];
  const float* ba   = (const float*)d_in[2];
  const float* va   = (const float*)d_in[3];
  const float* eWih = (const float*)d_in[4];
  const float* eWhh = (const float*)d_in[5];
  const float* ebih = (const float*)d_in[6];
  const float* ebhh = (const float*)d_in[7];
  const float* dWih = (const float*)d_in[8];
  const float* dWhh = (const float*)d_in[9];
  const float* dbih = (const float*)d_in[10];
  const float* dbhh = (const float*)d_in[11];
  const float* Wt   = (const float*)d_in[12];
  const float* bt   = (const float*)d_in[13];
  const float* vt   = (const float*)d_in[14];
  const float* Wfc  = (const float*)d_in[15];
  const float* bfc  = (const float*)d_in[16];
  float* out = (float*)d_out;

  char* ws = (char*)d_ws;
  size_t off = 0;
  bf16* encW    = (bf16*)(ws + off); off += (size_t)768*288*sizeof(bf16);
  bf16* wtEncP  = (bf16*)(ws + off); off += (size_t)256*288*sizeof(bf16);
  bf16* wtDec   = (bf16*)(ws + off); off += (size_t)256*256*sizeof(bf16);
  bf16* whhD    = (bf16*)(ws + off); off += (size_t)768*256*sizeof(bf16);
  bf16* wihPD   = (bf16*)(ws + off); off += (size_t)768*288*sizeof(bf16);
  float* treprs = (float*)(ws + off); off += (size_t)B_TOT*T_LEN*3*sizeof(float);
  float* h_enc  = (float*)(ws + off); off += (size_t)B_TOT*H_DIM*sizeof(float);
  unsigned char* eo8 = (unsigned char*)(ws + off); off += (size_t)B_TOT*T_LEN*H_DIM;
  unsigned char* ep8 = (unsigned char*)(ws + off); off += (size_t)B_TOT*T_LEN*H_DIM;
  // total: ~133.6 MiB

  if (ws_size < off) return;   // diagnostic: clean absmax-fail instead of fault

  convert_kernel<<<(768*288 + 255)/256, 256, 0, stream>>>(
      eWhh, eWih, Wt, dWhh, dWih, encW, wtEncP, wtDec, whhD, wihPD);
  agent_attn_kernel<<<B_TOT*T_LEN/256, 256, 0, stream>>>(x, Wa, ba, va, treprs);
  encoder_kernel<<<B_TOT/16, 512, 0, stream>>>(encW, wtEncP, eWih, ebih, ebhh,
                                               treprs, eo8, ep8, h_enc);
  decoder_kernel<<<B_TOT/4, 512, 0, stream>>>(x, wtDec, bt, vt, wihPD, whhD, dbih, dbhh,
                                              Wfc, bfc, eo8, ep8, h_enc, out);
}

// Round 6
// 2671.134 us; speedup vs baseline: 1.5983x; 1.5983x over previous
//
#include <hip/hip_runtime.h>
#include <hip/hip_bf16.h>

typedef __hip_bfloat16 bf16;
typedef __attribute__((ext_vector_type(8))) short s16x8;
typedef __attribute__((ext_vector_type(4))) float f32x4;
typedef __attribute__((ext_vector_type(2))) float f32x2;

#define B_TOT 1024
#define T_LEN 256
#define H_DIM 256
#define PRED_LEN 16

__device__ __forceinline__ float b2f(short u) {
  union { unsigned int i; float f; } c;
  c.i = ((unsigned int)(unsigned short)u) << 16;
  return c.f;
}
__device__ __forceinline__ float fsig(float x) {
  return __builtin_amdgcn_rcpf(1.f + __expf(-x));
}
__device__ __forceinline__ float ftanh(float x) {
  return 1.f - 2.f * __builtin_amdgcn_rcpf(1.f + __expf(2.f * x));
}
__device__ __forceinline__ f32x4 mfma16(s16x8 a, s16x8 b, f32x4 c) {
  return __builtin_amdgcn_mfma_f32_16x16x32_bf16(a, b, c, 0, 0, 0);
}
template <int HI>
__device__ __forceinline__ f32x2 fp8pk2f(unsigned int pk) {
  return __builtin_amdgcn_cvt_pk_f32_fp8(pk, HI);
}
__device__ __forceinline__ unsigned char f2fp8(float v) {
  return (unsigned char)(__builtin_amdgcn_cvt_pk_fp8_f32(v, v, 0, 0) & 0xff);
}
// pack 8 bf16 (as shorts) -> 8 fp8 in uint2
__device__ __forceinline__ uint2 pk8fp8(s16x8 hv) {
  unsigned int lo = 0, hi = 0;
  lo = __builtin_amdgcn_cvt_pk_fp8_f32(b2f(hv[0]), b2f(hv[1]), lo, 0);
  lo = __builtin_amdgcn_cvt_pk_fp8_f32(b2f(hv[2]), b2f(hv[3]), lo, 1);
  hi = __builtin_amdgcn_cvt_pk_fp8_f32(b2f(hv[4]), b2f(hv[5]), hi, 0);
  hi = __builtin_amdgcn_cvt_pk_fp8_f32(b2f(hv[6]), b2f(hv[7]), hi, 1);
  uint2 w; w.x = lo; w.y = hi; return w;
}

// ---------- Kernel 0: pack fp32 weights -> bf16 ws layouts ------------------
// encWF : 48 tiles x 8 kc x 64 lanes x 8 bf16, fragment-linear B-frags of eWhh
// wtEncF: 16 tiles x 8 kc x 64 lanes x 8 bf16, frag-linear of Wt[:,256:512]
// wtDec (256x256): Wt[:,0:256]; whhD (768x256); wihPD (768x288 pad of 265)
__global__ __launch_bounds__(256) void convert_kernel(
    const float* __restrict__ eWhh, const float* __restrict__ Wt,
    const float* __restrict__ dWhh, const float* __restrict__ dWih,
    bf16* __restrict__ encWF, bf16* __restrict__ wtEncF,
    bf16* __restrict__ wtDec, bf16* __restrict__ whhD, bf16* __restrict__ wihPD)
{
  int i = blockIdx.x*256 + threadIdx.x;
  if (i < 24576) {           // encWF fragment slots
    int l = i & 63, kc = (i>>6)&7, tile = i>>9;
    int j = tile*16 + (l&15);
    int k = kc*32 + ((l>>4)&3)*8;
    #pragma unroll
    for (int e = 0; e < 8; ++e)
      encWF[i*8+e] = __float2bfloat16(eWhh[j*256 + k + e]);
  } else if (i < 32768) {    // wtEncF fragment slots
    int s = i - 24576;
    int l = s & 63, kc = (s>>6)&7, tile = s>>9;
    int j = tile*16 + (l&15);
    int k = kc*32 + ((l>>4)&3)*8;
    #pragma unroll
    for (int e = 0; e < 8; ++e)
      wtEncF[s*8+e] = __float2bfloat16(Wt[j*512 + 256 + k + e]);
  }
  if (i < 768*288) {
    int g = i / 288, k = i - g*288;
    wihPD[i] = __float2bfloat16((k < 265) ? dWih[g*265 + k] : 0.f);
  }
  if (i < 256*256) {
    int g = i >> 8, k = i & 255;
    wtDec[i] = __float2bfloat16(Wt[g*512 + k]);
  }
  if (i < 768*256) whhD[i] = __float2bfloat16(dWhh[i]);
}

// ---------- Kernel 1: per-(b,t) agent attention -> timestep_reprs (f32) ----
__global__ __launch_bounds__(256) void agent_attn_kernel(
    const float* __restrict__ x, const float* __restrict__ Wa,
    const float* __restrict__ ba, const float* __restrict__ va,
    float* __restrict__ treprs)
{
  __shared__ float w0[256], w1[256], w2[256], baL[256], vaL[256];
  int tid = threadIdx.x;
  w0[tid] = Wa[tid*3+0];
  w1[tid] = Wa[tid*3+1];
  w2[tid] = Wa[tid*3+2];
  baL[tid] = ba[tid];
  vaL[tid] = va[tid];
  __syncthreads();
  long idx = (long)blockIdx.x * 256 + tid;   // b*T + t
  float xa[9];
  #pragma unroll
  for (int i = 0; i < 9; ++i) xa[i] = x[idx*9 + i];
  float s0 = 0.f, s1 = 0.f, s2 = 0.f;
  for (int h = 0; h < 256; ++h) {
    float a0 = w0[h], a1 = w1[h], a2 = w2[h], bb = baL[h], vv = vaL[h];
    s0 += ftanh(a0*xa[0] + a1*xa[1] + a2*xa[2] + bb) * vv;
    s1 += ftanh(a0*xa[3] + a1*xa[4] + a2*xa[5] + bb) * vv;
    s2 += ftanh(a0*xa[6] + a1*xa[7] + a2*xa[8] + bb) * vv;
  }
  float mx = fmaxf(s0, fmaxf(s1, s2));
  float e0 = __expf(s0-mx), e1 = __expf(s1-mx), e2 = __expf(s2-mx);
  float inv = __builtin_amdgcn_rcpf(e0+e1+e2);
  e0 *= inv; e1 *= inv; e2 *= inv;
  treprs[idx*3+0] = e0*xa[0] + e1*xa[3] + e2*xa[6];
  treprs[idx*3+1] = e0*xa[1] + e1*xa[4] + e2*xa[7];
  treprs[idx*3+2] = e0*xa[2] + e1*xa[5] + e2*xa[8];
}

// ---------- Kernel 2: weight-stationary encoder GRU scan -------------------
// 64 wgs x 512 thr; wg owns 16 batch rows. Each wave holds its 6 gate
// B-tiles (r/z/n pairs) resident in 192 VGPRs for all 256 steps. A-frags
// come from a fragment-linear LDS buffer (conflict-free ds_read_b128).
// x-part of all gates via VALU. enc_out emitted fp8; enc_proj external.
__global__ __launch_bounds__(512) void encoder_kernel(
    const bf16* __restrict__ encWF, const float* __restrict__ eWih,
    const float* __restrict__ ebih, const float* __restrict__ ebhh,
    const float* __restrict__ treprs, unsigned char* __restrict__ eo8,
    float* __restrict__ h_enc)
{
  __shared__ __align__(16) bf16  hbF[8*64*8];     // frag-linear h (8 KB)
  __shared__ __align__(16) float hf[16*260];      // fp32 recurrent state
  __shared__ __align__(16) f32x4 wihAll[768];     // (w0,w1,w2, bias)
  __shared__ float bhhnL[256];
  __shared__ float xtL[2][64];

  const int tid = threadIdx.x;
  const int b0 = blockIdx.x * 16;

  for (int i = tid; i < 768; i += 512) {
    f32x4 w;
    w.x = eWih[i*3+0]; w.y = eWih[i*3+1]; w.z = eWih[i*3+2];
    w.w = (i < 512) ? (ebih[i] + ebhh[i]) : ebih[i];
    wihAll[i] = w;
    if (i >= 512) bhhnL[i-512] = ebhh[i];
  }
  for (int i = tid; i < 16*260; i += 512) hf[i] = 0.f;
  for (int i = tid; i < 8*64*8; i += 512) hbF[i] = __float2bfloat16(0.f);
  if (tid < 64) {
    int m = tid >> 2, f = tid & 3;
    xtL[0][tid] = (f < 3) ? treprs[((long)(b0+m)*T_LEN + 0)*3 + f] : 0.f;
  }

  const int lane = tid & 63;
  const int wv   = tid >> 6;
  const int nrow = lane & 15;
  const int quad = lane >> 4;

  // resident weight fragments: u 0,1=r  2,3=z  4,5=n  (c = u&1)
  s16x8 wf[48];
  #pragma unroll
  for (int u = 0; u < 6; ++u) {
    int tile = (u < 2) ? (2*wv + u) : (u < 4) ? (16 + 2*wv + (u-2))
                                              : (32 + 2*wv + (u-4));
    #pragma unroll
    for (int kc = 0; kc < 8; ++kc)
      wf[u*8+kc] = *(const s16x8*)(encWF + ((tile*8 + kc)*64 + lane)*8);
  }
  __syncthreads();

  for (int t = 0; t < 256; ++t) {
    // ---- read phase: A-frags + eo8[t-1] from hbF (h_t) ----
    s16x8 afr[8];
    #pragma unroll
    for (int kc = 0; kc < 8; ++kc)
      afr[kc] = *(const s16x8*)&hbF[(kc*64 + lane)*8];
    if (t >= 1) {
      s16x8 hv = *(const s16x8*)&hbF[tid*8];
      int m = tid & 15, k = (tid>>6)*32 + ((tid>>4)&3)*8;
      *(uint2*)(eo8 + ((long)(b0+m)*T_LEN + (t-1))*H_DIM + k) = pk8fp8(hv);
    }
    __syncthreads();

    // ---- MFMA from resident weights ----
    f32x4 acc[6] = {};
    #pragma unroll
    for (int kc = 0; kc < 8; ++kc) {
      #pragma unroll
      for (int u = 0; u < 6; ++u)
        acc[u] = mfma16(afr[kc], wf[u*8+kc], acc[u]);
    }

    // prefetch next xt
    if (t < 255 && tid < 64) {
      int m = tid >> 2, f = tid & 3;
      xtL[(t+1)&1][tid] = (f < 3) ? treprs[((long)(b0+m)*T_LEN + (t+1))*3 + f] : 0.f;
    }

    // ---- combine -> h_{t+1} ----
    #pragma unroll
    for (int r = 0; r < 4; ++r) {
      int m = quad*4 + r;
      float x0 = xtL[t & 1][m*4+0];
      float x1 = xtL[t & 1][m*4+1];
      float x2 = xtL[t & 1][m*4+2];
      #pragma unroll
      for (int c = 0; c < 2; ++c) {
        int j = wv*32 + c*16 + nrow;
        f32x4 wr = wihAll[j];
        f32x4 wz = wihAll[256+j];
        f32x4 wn = wihAll[512+j];
        float rg = fsig(wr.x*x0 + wr.y*x1 + wr.z*x2 + wr.w + acc[c][r]);
        float zg = fsig(wz.x*x0 + wz.y*x1 + wz.z*x2 + wz.w + acc[2+c][r]);
        float ng = ftanh(wn.x*x0 + wn.y*x1 + wn.z*x2 + wn.w
                         + rg*(acc[4+c][r] + bhhnL[j]));
        float hold = hf[m*260 + j];
        float hnew = ng + zg*(hold - ng);
        hf[m*260 + j] = hnew;
        int qp = (c*16 + nrow) >> 3;           // frag-linear scatter of h
        hbF[(wv*64 + qp*16 + m)*8 + (nrow & 7)] = __float2bfloat16(hnew);
      }
    }
    __syncthreads();
  }

  // final eo8[255] = h_256
  {
    s16x8 hv = *(const s16x8*)&hbF[tid*8];
    int m = tid & 15, k = (tid>>6)*32 + ((tid>>4)&3)*8;
    *(uint2*)(eo8 + ((long)(b0+m)*T_LEN + 255)*H_DIM + k) = pk8fp8(hv);
  }
  for (int i = tid; i < 16*256; i += 512) {
    int m = i >> 8, j = i & 255;
    h_enc[(long)(b0+m)*H_DIM + j] = hf[m*260 + j];
  }
}

// ---------- Kernel 3: enc_proj GEMM: ep8 = fp8( eo8 @ WtEnc^T ) ------------
// 4096 wgs x 256 thr; wg handles 64 rows of M = B*T.
__global__ __launch_bounds__(256) void proj_kernel(
    const unsigned char* __restrict__ eo8, const bf16* __restrict__ wtEncF,
    unsigned char* __restrict__ ep8)
{
  __shared__ __align__(16) bf16 Asm[4*8*64*8];        // 32 KB frag-linear A
  __shared__ __align__(16) unsigned char Cst[64*256]; // 16 KB fp8 C staging
  const int tid = threadIdx.x;
  const long R0 = (long)blockIdx.x * 64;
  const int lane = tid & 63, wv = tid >> 6;
  const int nrow = lane & 15, quad = lane >> 4;

  // stage A: decode fp8 rows -> bf16 fragments
  #pragma unroll
  for (int s8 = 0; s8 < 8; ++s8) {
    int s = tid + s8*256;
    int l = s & 63, kc = (s>>6)&7, at = s>>9;
    int m = at*16 + (l&15), k = kc*32 + ((l>>4)&3)*8;
    uint2 v = *(const uint2*)(eo8 + (R0+m)*H_DIM + k);
    s16x8 o; f32x2 d;
    d = fp8pk2f<0>(v.x); o[0] = __bfloat16_as_short(__float2bfloat16(d.x)); o[1] = __bfloat16_as_short(__float2bfloat16(d.y));
    d = fp8pk2f<1>(v.x); o[2] = __bfloat16_as_short(__float2bfloat16(d.x)); o[3] = __bfloat16_as_short(__float2bfloat16(d.y));
    d = fp8pk2f<0>(v.y); o[4] = __bfloat16_as_short(__float2bfloat16(d.x)); o[5] = __bfloat16_as_short(__float2bfloat16(d.y));
    d = fp8pk2f<1>(v.y); o[6] = __bfloat16_as_short(__float2bfloat16(d.x)); o[7] = __bfloat16_as_short(__float2bfloat16(d.y));
    *(s16x8*)&Asm[s*8] = o;
  }
  __syncthreads();

  f32x4 acc[16];
  #pragma unroll
  for (int n = 0; n < 16; ++n) acc[n] = f32x4{0.f,0.f,0.f,0.f};
  #pragma unroll
  for (int kc = 0; kc < 8; ++kc) {
    s16x8 a = *(const s16x8*)&Asm[((wv*8 + kc)*64 + lane)*8];
    #pragma unroll
    for (int nt = 0; nt < 16; ++nt) {
      s16x8 b = *(const s16x8*)(wtEncF + ((nt*8 + kc)*64 + lane)*8);
      acc[nt] = mfma16(a, b, acc[nt]);
    }
  }
  #pragma unroll
  for (int nt = 0; nt < 16; ++nt)
    #pragma unroll
    for (int r = 0; r < 4; ++r)
      Cst[(wv*16 + quad*4 + r)*256 + nt*16 + nrow] = f2fp8(acc[nt][r]);
  __syncthreads();

  {
    int row = tid >> 2, seg = tid & 3;
    #pragma unroll
    for (int p = 0; p < 4; ++p)
      *(uint4*)(ep8 + (R0+row)*H_DIM + seg*64 + p*16) =
          *(const uint4*)&Cst[row*256 + seg*64 + p*16];
  }
}

// ---------- Kernel 4: persistent decoder (attention + GRU), 16 steps -------
__global__ __launch_bounds__(512) void decoder_kernel(
    const float* __restrict__ x, const bf16* __restrict__ wtDec,
    const float* __restrict__ bt, const float* __restrict__ vt,
    const bf16* __restrict__ wihPD, const bf16* __restrict__ whhD,
    const float* __restrict__ dbih, const float* __restrict__ dbhh,
    const float* __restrict__ Wfc, const float* __restrict__ bfc,
    const unsigned char* __restrict__ eo8, const unsigned char* __restrict__ ep8,
    const float* __restrict__ h_enc, float* __restrict__ out)
{
  __shared__ __align__(16) float hfL[4*260];
  __shared__ __align__(16) bf16  hbL[16*264];
  __shared__ __align__(16) float qL[4*260];
  __shared__ float twL[4*260];
  __shared__ __align__(16) bf16  inpb[16*296];
  __shared__ __align__(16) float vtL[256];
  __shared__ float btL[256];
  __shared__ float bihL[768];
  __shared__ float bhhL[768];
  __shared__ __align__(16) float WfcL[9*260];
  __shared__ float bfcL[9];
  __shared__ float decin[48];
  __shared__ __align__(16) float scratch[4096];

  const int tid = threadIdx.x;
  const int b0 = blockIdx.x * 4;

  for (int i = tid; i < 256; i += 512) { vtL[i] = vt[i]; btL[i] = bt[i]; }
  for (int i = tid; i < 768; i += 512) { bihL[i] = dbih[i]; bhhL[i] = dbhh[i]; }
  for (int i = tid; i < 9*256; i += 512) { int o = i >> 8, k = i & 255; WfcL[o*260+k] = Wfc[i]; }
  if (tid < 9) bfcL[tid] = bfc[tid];
  for (int i = tid; i < 4*260; i += 512) { int m = i/260, j = i - m*260; hfL[i] = (j < 256) ? h_enc[(long)(b0+m)*H_DIM + j] : 0.f; }
  for (int i = tid; i < 16*264; i += 512) hbL[i] = __float2bfloat16(0.f);
  for (int i = tid; i < 16*296; i += 512) inpb[i] = __float2bfloat16(0.f);
  if (tid < 36) { int b = tid/9, o = tid - b*9; decin[b*12+o] = x[((long)(b0+b)*T_LEN + (T_LEN-1))*9 + o]; }
  __syncthreads();

  const int lane = tid & 63;
  const int wv   = tid >> 6;
  const int nrow = lane & 15;
  const int quad = lane >> 4;

  const bf16* qptr[2];
  #pragma unroll
  for (int u = 0; u < 2; ++u) {
    int g = wv*32 + u*16 + nrow;
    qptr[u] = wtDec + (long)g*H_DIM + quad*8;
  }
  const bf16* giptr[6];
  const bf16* ghptr[6];
  #pragma unroll
  for (int u = 0; u < 6; ++u) {
    int tile = (u < 2) ? (2*wv + u) : (u < 4) ? (16 + 2*wv + (u-2)) : (32 + 2*wv + (u-4));
    int g = tile*16 + nrow;
    giptr[u] = wihPD + (long)g*288 + quad*8;
    ghptr[u] = whhD + (long)g*H_DIM + quad*8;
  }

  for (int s = 0; s < PRED_LEN; ++s) {
    for (int i = tid; i < 4*256; i += 512) {
      int m = i >> 8, j = i & 255;
      hbL[m*264 + j] = __float2bfloat16(hfL[m*260 + j]);
    }
    __syncthreads();

    {
      f32x4 qacc[2] = {};
      #pragma unroll
      for (int kc = 0; kc < 8; ++kc) {
        s16x8 a = *(const s16x8*)&hbL[nrow*264 + kc*32 + quad*8];
        #pragma unroll
        for (int u = 0; u < 2; ++u) {
          s16x8 bw = *(const s16x8*)(qptr[u] + kc*32);
          qacc[u] = mfma16(a, bw, qacc[u]);
        }
      }
      if (quad == 0) {
        #pragma unroll
        for (int u = 0; u < 2; ++u) {
          int g = wv*32 + u*16 + nrow;
          #pragma unroll
          for (int r = 0; r < 4; ++r)
            qL[r*260 + g] = qacc[u][r] + btL[g];
        }
      }
    }
    __syncthreads();

    {
      int bb = tid >> 7, tt = tid & 127;
      #pragma unroll
      for (int p = 0; p < 2; ++p) {
        int t = tt + p*128;
        const uint4* ep4 = (const uint4*)(ep8 + ((long)(b0+bb)*T_LEN + t)*H_DIM);
        const float* qrow = &qL[bb*260];
        float ssum = 0.f;
        for (int kc = 0; kc < 16; ++kc) {
          uint4 pv = ep4[kc];
          float vals[16];
          f32x2 d;
          d = fp8pk2f<0>(pv.x); vals[0]=d.x;  vals[1]=d.y;
          d = fp8pk2f<1>(pv.x); vals[2]=d.x;  vals[3]=d.y;
          d = fp8pk2f<0>(pv.y); vals[4]=d.x;  vals[5]=d.y;
          d = fp8pk2f<1>(pv.y); vals[6]=d.x;  vals[7]=d.y;
          d = fp8pk2f<0>(pv.z); vals[8]=d.x;  vals[9]=d.y;
          d = fp8pk2f<1>(pv.z); vals[10]=d.x; vals[11]=d.y;
          d = fp8pk2f<0>(pv.w); vals[12]=d.x; vals[13]=d.y;
          d = fp8pk2f<1>(pv.w); vals[14]=d.x; vals[15]=d.y;
          #pragma unroll
          for (int j = 0; j < 16; ++j)
            ssum += ftanh(vals[j] + qrow[kc*16+j]) * vtL[kc*16+j];
        }
        scratch[bb*256 + t] = ssum;
      }
    }
    __syncthreads();

    if (wv < 4) {
      float v4[4];
      float mx = -1e30f;
      #pragma unroll
      for (int i = 0; i < 4; ++i) { v4[i] = scratch[wv*256 + lane + 64*i]; mx = fmaxf(mx, v4[i]); }
      #pragma unroll
      for (int off = 1; off < 64; off <<= 1) mx = fmaxf(mx, __shfl_xor(mx, off));
      float sum = 0.f;
      #pragma unroll
      for (int i = 0; i < 4; ++i) { v4[i] = __expf(v4[i] - mx); sum += v4[i]; }
      #pragma unroll
      for (int off = 1; off < 64; off <<= 1) sum += __shfl_xor(sum, off);
      float inv = __builtin_amdgcn_rcpf(sum);
      #pragma unroll
      for (int i = 0; i < 4; ++i) twL[wv*260 + lane + 64*i] = v4[i] * inv;
    }
    __syncthreads();

    {
      int tq = tid >> 7, b = (tid >> 5) & 3, h8 = (tid & 31) * 8;
      const unsigned char* eob = eo8 + ((long)(b0+b)*T_LEN + tq*64)*H_DIM + h8;
      const float* tw = &twL[b*260 + tq*64];
      float c[8] = {0.f,0.f,0.f,0.f,0.f,0.f,0.f,0.f};
      for (int t = 0; t < 64; ++t) {
        uint2 ev = *(const uint2*)(eob + (long)t*H_DIM);
        float w = tw[t];
        f32x2 d;
        d = fp8pk2f<0>(ev.x); c[0] += w*d.x; c[1] += w*d.y;
        d = fp8pk2f<1>(ev.x); c[2] += w*d.x; c[3] += w*d.y;
        d = fp8pk2f<0>(ev.y); c[4] += w*d.x; c[5] += w*d.y;
        d = fp8pk2f<1>(ev.y); c[6] += w*d.x; c[7] += w*d.y;
      }
      #pragma unroll
      for (int j = 0; j < 8; ++j) scratch[tq*1024 + b*256 + h8 + j] = c[j];
    }
    __syncthreads();
    {
      #pragma unroll
      for (int p = 0; p < 2; ++p) {
        int idx = tid + p*512;
        int b = idx >> 8, h = idx & 255;
        float sum = scratch[b*256 + h] + scratch[1024 + b*256 + h]
                  + scratch[2048 + b*256 + h] + scratch[3072 + b*256 + h];
        inpb[b*296 + 9 + h] = __float2bfloat16(sum);
      }
      if (tid < 36) { int b = tid/9, o = tid - b*9; inpb[b*296 + o] = __float2bfloat16(decin[b*12 + o]); }
    }
    __syncthreads();

    {
      f32x4 gia[6] = {};
      #pragma unroll
      for (int kc = 0; kc < 9; ++kc) {
        s16x8 a = *(const s16x8*)&inpb[nrow*296 + kc*32 + quad*8];
        #pragma unroll
        for (int u = 0; u < 6; ++u) {
          s16x8 bw = *(const s16x8*)(giptr[u] + kc*32);
          gia[u] = mfma16(a, bw, gia[u]);
        }
      }
      f32x4 gha[6] = {};
      #pragma unroll
      for (int kc = 0; kc < 8; ++kc) {
        s16x8 a = *(const s16x8*)&hbL[nrow*264 + kc*32 + quad*8];
        #pragma unroll
        for (int u = 0; u < 6; ++u) {
          s16x8 bw = *(const s16x8*)(ghptr[u] + kc*32);
          gha[u] = mfma16(a, bw, gha[u]);
        }
      }
      if (quad == 0) {
        #pragma unroll
        for (int c = 0; c < 2; ++c) {
          int j = wv*32 + c*16 + nrow;
          #pragma unroll
          for (int r = 0; r < 4; ++r) {
            float rg = fsig(gia[c][r]   + bihL[j]     + gha[c][r]   + bhhL[j]);
            float zg = fsig(gia[2+c][r] + bihL[256+j] + gha[2+c][r] + bhhL[256+j]);
            float ng = ftanh(gia[4+c][r] + bihL[512+j] + rg*(gha[4+c][r] + bhhL[512+j]));
            float hold = hfL[r*260 + j];
            hfL[r*260 + j] = ng + zg*(hold - ng);
          }
        }
      }
    }
    __syncthreads();

    if (tid < 288) {
      int b = tid / 72, rem = tid - b*72;
      int o = rem >> 3, ch = rem & 7;
      float ps = 0.f;
      #pragma unroll
      for (int k = ch*32; k < ch*32 + 32; ++k)
        ps += hfL[b*260 + k] * WfcL[o*260 + k];
      scratch[tid] = ps;
    }
    __syncthreads();
    if (tid < 36) {
      int b = tid / 9, o = tid - b*9;
      float sum = bfcL[o];
      #pragma unroll
      for (int ch = 0; ch < 8; ++ch) sum += scratch[b*72 + o*8 + ch];
      out[((long)(b0+b)*PRED_LEN + s)*9 + o] = sum;
      decin[b*12 + o] = sum;
    }
    __syncthreads();
  }
}

extern "C" void kernel_launch(void* const* d_in, const int* in_sizes, int n_in,
                              void* d_out, int out_size, void* d_ws, size_t ws_size,
                              hipStream_t stream)
{
  const float* x    = (const float*)d_in[0];
  const float* Wa   = (const float*)d_in[1];
  const float* ba   = (const float*)d_in[2];
  const float* va   = (const float*)d_in[3];
  const float* eWih = (const float*)d_in[4];
  const float* eWhh = (const float*)d_in[5];
  const float* ebih = (const float*)d_in[6];
  const float* ebhh = (const float*)d_in[7];
  const float* dWih = (const float*)d_in[8];
  const float* dWhh = (const float*)d_in[9];
  const float* dbih = (const float*)d_in[10];
  const float* dbhh = (const float*)d_in[11];
  const float* Wt   = (const float*)d_in[12];
  const float* bt   = (const float*)d_in[13];
  const float* vt   = (const float*)d_in[14];
  const float* Wfc  = (const float*)d_in[15];
  const float* bfc  = (const float*)d_in[16];
  float* out = (float*)d_out;

  char* ws = (char*)d_ws;
  size_t off = 0;
  bf16* encWF   = (bf16*)(ws + off); off += (size_t)48*8*64*8*sizeof(bf16);
  bf16* wtEncF  = (bf16*)(ws + off); off += (size_t)16*8*64*8*sizeof(bf16);
  bf16* wtDec   = (bf16*)(ws + off); off += (size_t)256*256*sizeof(bf16);
  bf16* whhD    = (bf16*)(ws + off); off += (size_t)768*256*sizeof(bf16);
  bf16* wihPD   = (bf16*)(ws + off); off += (size_t)768*288*sizeof(bf16);
  float* treprs = (float*)(ws + off); off += (size_t)B_TOT*T_LEN*3*sizeof(float);
  float* h_enc  = (float*)(ws + off); off += (size_t)B_TOT*H_DIM*sizeof(float);
  unsigned char* eo8 = (unsigned char*)(ws + off); off += (size_t)B_TOT*T_LEN*H_DIM;
  unsigned char* ep8 = (unsigned char*)(ws + off); off += (size_t)B_TOT*T_LEN*H_DIM;
  // total ~133.4 MiB

  if (ws_size < off) return;

  convert_kernel<<<(768*288 + 255)/256, 256, 0, stream>>>(
      eWhh, Wt, dWhh, dWih, encWF, wtEncF, wtDec, whhD, wihPD);
  agent_attn_kernel<<<B_TOT*T_LEN/256, 256, 0, stream>>>(x, Wa, ba, va, treprs);
  encoder_kernel<<<B_TOT/16, 512, 0, stream>>>(encWF, eWih, ebih, ebhh,
                                               treprs, eo8, h_enc);
  proj_kernel<<<B_TOT*T_LEN/64, 256, 0, stream>>>(eo8, wtEncF, ep8);
  decoder_kernel<<<B_TOT/4, 512, 0, stream>>>(x, wtDec, bt, vt, wihPD, whhD, dbih, dbhh,
                                              Wfc, bfc, eo8, ep8, h_enc, out);
}